// Round 1
// baseline (91577.545 us; speedup 1.0000x reference)
//
#include <hip/hip_runtime.h>
#include <hip/hip_bf16.h>

// Persistent cooperative RNN kernel for MI355X (gfx950) — epoch-tagged
// dataflow, single-hop split-K reductions.
// 256 WGs x 512 threads, 1 WG/CU (~152KB LDS). Each WG owns 4 hidden rows =>
// 16 gate rows of every 4H weight matrix. Cross-WG broadcasts (h/c, dhx, dh1,
// dh2) are 8-byte (f32 value, u32 epoch) pairs written with agent-scope 64-bit
// atomic stores, consumed by polling coherent (sc0 sc1) 16B loads.
// The small matvecs (cls/fut per decoder iter) are now SINGLE-HOP: each WG
// adds its 4-column split-K partial directly into L3 accumulators with native
// global_atomic_add_f32 (4 banks/output to bound same-address serialization),
// releases with s_waitcnt vmcnt(0), then bumps a bank counter; consumers poll
// the 4 counters until they sum to 256 and then read the 4 banks. This removes
// the 8-WG reducer middleman (one full L3 visibility+detect leg per chain) and
// all partial-pair store traffic. Accumulator regions rotate over 4 steps and
// are re-zeroed 2 steps ahead by WGs 40-47; a one-time software grid barrier
// orders the initial zeroing (workspace arrives poisoned 0xAA).
// h(t-1) is cached in LDS (hprev) so R1 never re-polls it; x(t+1) prefetched.

typedef unsigned short u16t;
typedef unsigned int u32t;
typedef unsigned long long u64t;

#define TSTEPS 2045
#define NWG 256
#define NTHR 512
#define SPINCAP 8192
#define MAGIC 0x5a5a5a5aU

// d_ws dword offsets
#define HENC  0        // [par][1024 pairs]  enc h
#define CENC  4096     // [par][1024 pairs]  enc c
#define DHX   8192     // [par][1024 pairs]  head dhx
#define DD1   12288    // [par][1024 pairs]  dec h1
#define DD2   16384    // [par][1024 pairs]  dec h2
#define ACCF  20480    // [rot4][ph3][o128][16] f32 atomic accumulators (4 banks+pad)
#define CNTF  45056    // [rot4][ph3][16] u32 bank counters (4 used + pad to 64B)
#define BARF  45248    // [NWG+1] u32 startup barrier flags (poison-safe)
#define ZTOT  24768    // dwords zeroed at init (ACC 24576 + CNT 192, contiguous)

struct Params {
  const void *X, *eWih, *eWhh, *ebih, *ebhh, *dWih, *dWhh, *dbih, *dbhh,
             *hxW, *hxb, *cxW, *cxb, *fusW, *fusb_g, *futW, *futb_g, *clsW, *clsb_g;
  float* ws;
  void* out;
};

struct SharedMem {
  alignas(16) float encW[16 * 1152];   // [row][Wih(128)|Whh(1024)] f32, 73728B
  alignas(16) u16t  decW[16 * 2048];   // [row][Wih(1024)|Whh(1024)] bf16, 65536B
  alignas(16) float xs[2048];          // staged vectors for dots
  alignas(16) float hprev[1024];       // cached h(t-1) (avoids R1 re-poll)
  alignas(16) float xsf[128];          // R1 fusion input [x(64)|fut(64)]
  float cls_sl[256], fut_sl[256];      // [o][j]: this WG's 4 columns
  float clsb[64], futb[64], fut_acc[64], dsbuf[64], xnext[64];
  float bias_e[16], bias_d[16], g16[16];
  float dcx_s[4], encc[4], hxb4[4], cxb4[4];
  int bail;
  int badcnt;
};

__device__ __forceinline__ float bfu(u16t u){
  union { u32t i; float f; } v; v.i = ((u32t)u) << 16; return v.f;
}
__device__ __forceinline__ u32t fbits(float f){
  union { float f; u32t u; } c; c.f = f; return c.u;
}
__device__ __forceinline__ u16t bf16bits(float v){
  __hip_bfloat16 b = __float2bfloat16(v);
  union { __hip_bfloat16 b; u16t u; } c; c.b = b; return c.u;
}
template<bool F32>
__device__ __forceinline__ float ldE(const void* p, int i){
  if (F32) return ((const float*)p)[i];
  return bfu(((const u16t*)p)[i]);
}
template<bool F32>
__device__ __forceinline__ u16t ldB(const void* p, int i){
  if (F32) return bf16bits(((const float*)p)[i]);
  return ((const u16t*)p)[i];
}
template<bool F32>
__device__ __forceinline__ void stO(void* p, int i, float v){
  if (F32) ((float*)p)[i] = v;
  else     ((u16t*)p)[i] = bf16bits(v);
}
__device__ __forceinline__ float sigm(float x){ return 1.f / (1.f + __expf(-x)); }
__device__ __forceinline__ float tanhx(float x){
  float e = __expf(-2.f * fabsf(x));
  float t = (1.f - e) / (1.f + e);
  return copysignf(t, x);
}
// Tagged-pair store: (value, epoch) as one 64-bit agent-scope atomic.
__device__ __forceinline__ void stp(float* rowbase, int idx, float v, u32t ep){
  u64t u = (u64t)fbits(v) | ((u64t)ep << 32);
  __hip_atomic_store((u64t*)rowbase + idx, u,
                     __ATOMIC_RELAXED, __HIP_MEMORY_SCOPE_AGENT);
}
__device__ __forceinline__ void stu32(u32t* p, u32t v){
  __hip_atomic_store(p, v, __ATOMIC_RELAXED, __HIP_MEMORY_SCOPE_AGENT);
}
// Coherent loads (device coherence point).
__device__ __forceinline__ float4 ld4c(const float* p){
  float4 r;
  asm volatile("global_load_dwordx4 %0, %1, off sc0 sc1\n\t"
               "s_waitcnt vmcnt(0)"
               : "=&v"(r) : "v"(p) : "memory");
  return r;
}
__device__ __forceinline__ uint4 ld4cu4(const u32t* p){
  uint4 r;
  asm volatile("global_load_dwordx4 %0, %1, off sc0 sc1\n\t"
               "s_waitcnt vmcnt(0)"
               : "=&v"(r) : "v"(p) : "memory");
  return r;
}
__device__ __forceinline__ u32t ld1cu(const u32t* p){
  u32t r;
  asm volatile("global_load_dword %0, %1, off sc0 sc1\n\t"
               "s_waitcnt vmcnt(0)"
               : "=&v"(r) : "v"(p) : "memory");
  return r;
}
// Two coherent 16B loads, single wait.
__device__ __forceinline__ void ld4c2(const float* p0, const float* p1,
                                      float4& a, float4& b){
  asm volatile(
    "global_load_dwordx4 %0, %2, off sc0 sc1\n\t"
    "global_load_dwordx4 %1, %3, off sc0 sc1\n\t"
    "s_waitcnt vmcnt(0)"
    : "=&v"(a), "=&v"(b)
    : "v"(p0), "v"(p1)
    : "memory");
}
// Native L3 (device-scope) atomic adds, no return.
__device__ __forceinline__ void gadd_f32(float* p, float v){
  asm volatile("global_atomic_add_f32 %0, %1, off sc1" :: "v"(p), "v"(v) : "memory");
}
__device__ __forceinline__ void gadd_u32(u32t* p, u32t v){
  asm volatile("global_atomic_add %0, %1, off sc1" :: "v"(p), "v"(v) : "memory");
}
// Poll one quad (2 tagged pairs) until both tags == ep.
__device__ __forceinline__ float2 poll2(const float* q, u32t ep, int* bail){
  float4 r; int sp = 0;
  for (;;){
    r = ld4c(q);
    if (fbits(r.y) == ep && fbits(r.w) == ep) break;
    if (*bail) break;
    if (++sp > SPINCAP){ *bail = 1; break; }
  }
  return float2{r.x, r.z};
}

// Half-wave (32 lanes) dot of GLOBAL weight row with f32 x (LDS), reduced.
template<bool F32>
__device__ __forceinline__ float hw_dot(const void* wbase, long off,
                                        const float* __restrict__ x,
                                        int K, int lane){
  float acc = 0.f;
  if (F32){
    const float* w = (const float*)wbase + off;
    for (int c = lane * 4; c < K; c += 128){
      float4 wv = *(const float4*)(w + c);
      float4 xv = *(const float4*)(x + c);
      acc = fmaf(wv.x, xv.x, acc); acc = fmaf(wv.y, xv.y, acc);
      acc = fmaf(wv.z, xv.z, acc); acc = fmaf(wv.w, xv.w, acc);
    }
  } else {
    const u16t* w = (const u16t*)wbase + off;
    for (int c = lane * 4; c < K; c += 128){
      ushort4 wv = *(const ushort4*)(w + c);
      float4  xv = *(const float4*)(x + c);
      acc = fmaf(bfu(wv.x), xv.x, acc); acc = fmaf(bfu(wv.y), xv.y, acc);
      acc = fmaf(bfu(wv.z), xv.z, acc); acc = fmaf(bfu(wv.w), xv.w, acc);
    }
  }
  #pragma unroll
  for (int o = 16; o; o >>= 1) acc += __shfl_xor(acc, o, 64);
  return acc;
}

// Un-reduced per-lane dot partials (reduce once with wred).
__device__ __forceinline__ float dotnr_f32(const float* __restrict__ w,
                                           const float* __restrict__ x,
                                           int K, int lane){
  float acc = 0.f;
  for (int c = lane * 4; c < K; c += 128){
    float4 wv = *(const float4*)(w + c);
    float4 xv = *(const float4*)(x + c);
    acc = fmaf(wv.x, xv.x, acc); acc = fmaf(wv.y, xv.y, acc);
    acc = fmaf(wv.z, xv.z, acc); acc = fmaf(wv.w, xv.w, acc);
  }
  return acc;
}
__device__ __forceinline__ float dotnr_bf16(const u16t* __restrict__ w,
                                            const float* __restrict__ x,
                                            int K, int lane){
  float acc = 0.f;
  for (int c = lane * 8; c < K; c += 256){
    uint4  wv = *(const uint4*)(w + c);
    float4 x0 = *(const float4*)(x + c);
    float4 x1 = *(const float4*)(x + c + 4);
    acc = fmaf(bfu((u16t)(wv.x & 0xffff)), x0.x, acc);
    acc = fmaf(bfu((u16t)(wv.x >> 16)),    x0.y, acc);
    acc = fmaf(bfu((u16t)(wv.y & 0xffff)), x0.z, acc);
    acc = fmaf(bfu((u16t)(wv.y >> 16)),    x0.w, acc);
    acc = fmaf(bfu((u16t)(wv.z & 0xffff)), x1.x, acc);
    acc = fmaf(bfu((u16t)(wv.z >> 16)),    x1.y, acc);
    acc = fmaf(bfu((u16t)(wv.w & 0xffff)), x1.z, acc);
    acc = fmaf(bfu((u16t)(wv.w >> 16)),    x1.w, acc);
  }
  return acc;
}
__device__ __forceinline__ float wred(float a){
  #pragma unroll
  for (int o = 16; o; o >>= 1) a += __shfl_xor(a, o, 64);
  return a;
}

// Single-hop split-K producer: wave 0 (tid<64). hval holds this WG's 4 dh
// components in lanes 0-3; broadcast in-wave, add 4-col partials into L3
// accumulators, release, bump bank counter.
__device__ __forceinline__ void partial_adds(float* ws, u32t* wsu, int rot, int ph,
                                             const SharedMem& S, int tid, int w,
                                             float hval){
  float h0 = __shfl(hval, 0, 64), h1 = __shfl(hval, 1, 64),
        h2 = __shfl(hval, 2, 64), h3 = __shfl(hval, 3, 64);
  const float* cs = S.cls_sl + tid * 4;
  const float* fs = S.fut_sl + tid * 4;
  float sv = cs[0]*h0 + cs[1]*h1 + cs[2]*h2 + cs[3]*h3;
  float fv = fs[0]*h0 + fs[1]*h1 + fs[2]*h2 + fs[3]*h3;
  float* bb = ws + ACCF + (size_t)(((rot * 3 + ph) * 128 + tid) * 16 + (w & 3));
  gadd_f32(bb, sv);
  gadd_f32(bb + 1024, fv);          // f outputs live 64 lines (1024 floats) up
  asm volatile("s_waitcnt vmcnt(0)" ::: "memory");   // release: adds committed at L3
  if (tid == 0) gadd_u32(wsu + CNTF + (rot * 3 + ph) * 16 + (w & 3), 1u);
}

// Consumer: poll 4 bank counters until sum==256, then read both bank lines.
__device__ __forceinline__ void sf_consume(float* ws, const u32t* wsu, int rot, int ph,
                                           SharedMem& S, int tid,
                                           float& dsv, float& fv){
  const u32t* cp = wsu + CNTF + (rot * 3 + ph) * 16;
  int sp = 0;
  for (;;){
    uint4 c = ld4cu4(cp);
    if (c.x + c.y + c.z + c.w == 256u) break;
    if (S.bail) break;
    if (++sp > SPINCAP){ S.bail = 1; break; }
  }
  const float* ap = ws + ACCF + (size_t)((rot * 3 + ph) * 128 + tid) * 16;
  float4 a, b;
  ld4c2(ap, ap + 1024, a, b);
  dsv = a.x + a.y + a.z + a.w + S.clsb[tid];
  fv  = fmaxf(b.x + b.y + b.z + b.w + S.futb[tid], 0.f);
}

template<bool F32>
__device__ void run(const Params& p, SharedMem& S){
  const int tid  = threadIdx.x;
  const int w    = blockIdx.x;
  const int hw   = tid >> 5;            // half-wave 0..15 -> one gate row each
  const int lane = tid & 31;
  const long grow = (long)((hw >> 2) * 1024 + 4 * w + (hw & 3));  // gate row
  float* ws = p.ws;
  u32t* wsu = (u32t*)p.ws;

  // ---------- init: zero atomic accumulators/counters, then grid barrier ----
  for (int i = w * NTHR + tid; i < ZTOT; i += NWG * NTHR)
    stu32(wsu + ACCF + i, 0u);
  asm volatile("s_waitcnt vmcnt(0)" ::: "memory");
  __syncthreads();
  if (tid == 0) stu32(wsu + BARF + w, MAGIC);
  if (w == 0){
    if (tid < NWG){
      int sp = 0;
      while (ld1cu(wsu + BARF + tid) != MAGIC && ++sp < (1 << 22)) {}
    }
    __syncthreads();
    if (tid == 0) stu32(wsu + BARF + NWG, MAGIC);
  }
  if (tid == 0){
    int sp = 0;
    while (ld1cu(wsu + BARF + NWG) != MAGIC && ++sp < (1 << 22)) {}
  }
  __syncthreads();

  // ---------- startup: stage per-WG weights into LDS ----------
  {
    float* er = S.encW + hw * 1152;
    for (int c = lane; c < 128; c += 32)  er[c]       = ldE<F32>(p.eWih, (int)(grow * 128 + c));
    for (int c = lane; c < 1024; c += 32) er[128 + c] = ldE<F32>(p.eWhh, (int)(grow * 1024 + c));
    u16t* dr = S.decW + hw * 2048;
    for (int c = lane; c < 1024; c += 32){
      dr[c]        = ldB<F32>(p.dWih, (int)(grow * 1024 + c));
      dr[1024 + c] = ldB<F32>(p.dWhh, (int)(grow * 1024 + c));
    }
  }
  // fus_W rows for this thread's two h outputs -> registers
  u32t fw[64];
  float fusb0, fusb1;
  {
    int h0 = 2 * tid, h1 = 2 * tid + 1;
    #pragma unroll
    for (int o = 0; o < 64; ++o){
      u16t lo = ldB<F32>(p.fusW, h0 * 64 + o);
      u16t hi = ldB<F32>(p.fusW, h1 * 64 + o);
      fw[o] = ((u32t)hi << 16) | lo;
    }
    fusb0 = ldE<F32>(p.fusb_g, h0);
    fusb1 = ldE<F32>(p.fusb_g, h1);
  }
  if (tid < 256){
    int o = tid >> 2, j = tid & 3;
    S.cls_sl[tid] = ldE<F32>(p.clsW, o * 1024 + 4 * w + j);
    S.fut_sl[tid] = ldE<F32>(p.futW, o * 1024 + 4 * w + j);
  }
  if (tid < 64){
    S.clsb[tid] = ldE<F32>(p.clsb_g, tid);
    S.futb[tid] = ldE<F32>(p.futb_g, tid);
    S.fut_acc[tid] = 0.f;
  }
  S.hprev[2 * tid] = 0.f; S.hprev[2 * tid + 1] = 0.f;   // h(-1) = 0
  if (tid < 16){
    int gr = (tid >> 2) * 1024 + 4 * w + (tid & 3);
    S.bias_e[tid] = ldE<F32>(p.ebih, gr) + ldE<F32>(p.ebhh, gr);
    S.bias_d[tid] = ldE<F32>(p.dbih, gr) + ldE<F32>(p.dbhh, gr);
  }
  if (tid < 4){
    S.hxb4[tid] = ldE<F32>(p.hxb, 4 * w + tid);
    S.cxb4[tid] = ldE<F32>(p.cxb, 4 * w + tid);
    S.encc[tid] = 0.f;
  }
  __syncthreads();

  for (int t = 0; t < TSTEPS; ++t){
    const int  par = t & 1;
    const int  rot = t & 3;
    const u32t ep  = (u32t)(t + 1);

    // ============ R1: encoder gates (only f3 is fresh; h cached in hprev) ====
    if (tid < 64){
      float xv = (t == 0) ? ldE<F32>(p.X, tid) : S.xnext[tid];
      float futv = 0.f;
      if (t > 0){
        float dsv, fv;
        sf_consume(ws, wsu, (t - 1) & 3, 2, S, tid, dsv, fv);
        futv = (S.fut_acc[tid] + fv) * (1.f / 3.f);
        S.fut_acc[tid] = 0.f;
        if (w == 10) stO<F32>(p.out, TSTEPS * 64 + ((t - 1) * 3 + 2) * 64 + tid, dsv);
      }
      S.xsf[tid] = xv;
      S.xsf[64 + tid] = futv;
    }
    __syncthreads();
    {
      float a = dotnr_f32(S.encW + hw * 1152, S.xsf, 128, lane)
              + dotnr_f32(S.encW + hw * 1152 + 128, S.hprev, 1024, lane);
      a = wred(a) + S.bias_e[hw];
      if (lane == 0) S.g16[hw] = a;
    }
    __syncthreads();
    if (tid < 4){
      float gi = sigm(S.g16[tid]), gf = sigm(S.g16[4 + tid]),
            gg = tanhx(S.g16[8 + tid]), go = sigm(S.g16[12 + tid]);
      float c = gf * S.encc[tid] + gi * gg;
      float h = go * tanhx(c);
      S.encc[tid] = c;
      stp(ws + HENC + par * 2048, 4 * w + tid, h, ep);
      stp(ws + CENC + par * 2048, 4 * w + tid, c, ep);
    }

    // ============ R2: heads dhx/dcx + enc_score (merged h+c poll) ============
    {
      const float* ph_ = ws + HENC + par * 2048 + tid * 4;
      const float* pc_ = ws + CENC + par * 2048 + tid * 4;
      float4 a, b; int sp = 0;
      for (;;){
        ld4c2(ph_, pc_, a, b);
        if (fbits(a.y) == ep && fbits(a.w) == ep &&
            fbits(b.y) == ep && fbits(b.w) == ep) break;
        if (S.bail) break;
        if (++sp > SPINCAP){ S.bail = 1; break; }
      }
      S.xs[2 * tid] = a.x;        S.xs[2 * tid + 1] = a.z;
      S.hprev[2 * tid] = a.x;     S.hprev[2 * tid + 1] = a.z;   // cache h(t)
      S.xs[1024 + 2 * tid] = b.x; S.xs[1025 + 2 * tid] = b.z;
    }
    __syncthreads();
    if (hw < 4){
      float d = fmaxf(hw_dot<F32>(p.hxW, (long)(4 * w + hw) * 1024, S.xs, 1024, lane)
                      + S.hxb4[hw], 0.f);
      if (lane == 0) stp(ws + DHX + par * 2048, 4 * w + hw, d, ep);
    } else if (hw < 8){
      int j = hw - 4;
      float d = fmaxf(hw_dot<F32>(p.cxW, (long)(4 * w + j) * 1024, S.xs + 1024, 1024, lane)
                      + S.cxb4[j], 0.f);
      if (lane == 0) S.dcx_s[j] = d;   // decoder c, reused by all 3 iters (ref bug)
    } else if (w >= 8 && w < 16){      // enc_score: 8 WGs x 8 half-waves
      int r = (w - 8) * 8 + (hw - 8);
      float s = hw_dot<F32>(p.clsW, (long)r * 1024, S.xs, 1024, lane) + S.clsb[r];
      if (lane == 0) stO<F32>(p.out, t * 64 + r, s);
    }
    __syncthreads();   // protect xs readers from R3's staging overwrite

    // ============ R3: decoder iter 1 (fusion_in = 0) ============
    {
      float2 v = poll2(ws + DHX + par * 2048 + tid * 4, ep, &S.bail);
      S.xs[2 * tid] = v.x; S.xs[2 * tid + 1] = v.y;
    }
    __syncthreads();
    {
      float a = wred(dotnr_bf16(S.decW + hw * 2048 + 1024, S.xs, 1024, lane)) + S.bias_d[hw];
      if (lane == 0) S.g16[hw] = a;
    }
    __syncthreads();
    {
      float hval = 0.f;
      if (tid < 4){
        float gi = sigm(S.g16[tid]), gf = sigm(S.g16[4 + tid]),
              gg = tanhx(S.g16[8 + tid]), go = sigm(S.g16[12 + tid]);
        float c = gf * S.dcx_s[tid] + gi * gg;
        hval = go * tanhx(c);
        stp(ws + DD1 + par * 2048, 4 * w + tid, hval, ep);
      }
      if (tid < 64){
        partial_adds(ws, wsu, rot, 0, S, tid, w, hval);
        S.xnext[tid] = ldE<F32>(p.X, (t + 1) * 64 + tid);   // prefetch x(t+1)
      }
    }
    // steady-state zeroer: clear rot t+2 regions (off-path, visible in 2 steps)
    if (w >= 40 && w < 48){
      const int r2 = (t + 2) & 3;
      for (int i = (w - 40) * NTHR + tid; i < 6144; i += 8 * NTHR)
        stu32(wsu + ACCF + r2 * 6144 + i, 0u);
      if (w == 40 && tid < 48) stu32(wsu + CNTF + r2 * 48 + tid, 0u);
      asm volatile("s_waitcnt vmcnt(0)" ::: "memory");
    }

    // ============ R4/R5: decoder iters 2,3 ============
    for (int di = 2; di <= 3; ++di){
      const int ph = di - 2;               // sf phase consumed this round
      {
        float2 v = poll2(ws + (di == 2 ? DD1 : DD2) + par * 2048 + tid * 4, ep, &S.bail);
        S.xs[1024 + 2 * tid] = v.x; S.xs[1025 + 2 * tid] = v.y;
      }
      __syncthreads();
      float accA = dotnr_bf16(S.decW + hw * 2048 + 1024, S.xs + 1024, 1024, lane);
      if (tid < 64){                       // wave 0: single-hop sf consume
        float dsv, fv;
        sf_consume(ws, wsu, rot, ph, S, tid, dsv, fv);
        S.dsbuf[tid] = dsv;
        S.fut_acc[tid] += fv;
        if (w == 8 + ph) stO<F32>(p.out, TSTEPS * 64 + (t * 3 + ph) * 64 + tid, dsv);
      }
      __syncthreads();
      {   // fusion_in = relu(fus_W @ ds + fus_b), per-thread 2 rows from VGPRs
        float a0 = fusb0, a1 = fusb1;
        #pragma unroll
        for (int o = 0; o < 64; ++o){
          float d = S.dsbuf[o];
          a0 = fmaf(bfu((u16t)(fw[o] & 0xffff)), d, a0);
          a1 = fmaf(bfu((u16t)(fw[o] >> 16)),    d, a1);
        }
        S.xs[2 * tid]     = fmaxf(a0, 0.f);
        S.xs[2 * tid + 1] = fmaxf(a1, 0.f);
      }
      __syncthreads();
      {
        float a = wred(accA + dotnr_bf16(S.decW + hw * 2048, S.xs, 1024, lane))
                + S.bias_d[hw];
        if (lane == 0) S.g16[hw] = a;
      }
      __syncthreads();
      {
        float hval = 0.f;
        if (tid < 4){
          float gi = sigm(S.g16[tid]), gf = sigm(S.g16[4 + tid]),
                gg = tanhx(S.g16[8 + tid]), go = sigm(S.g16[12 + tid]);
          float c = gf * S.dcx_s[tid] + gi * gg;
          hval = go * tanhx(c);
          if (di == 2) stp(ws + DD2 + par * 2048, 4 * w + tid, hval, ep);
        }
        if (tid < 64) partial_adds(ws, wsu, rot, di - 1, S, tid, w, hval);
      }
    }
  }

  // epilogue: last step's ds3 (its consumer round never runs)
  if (w == 10 && tid < 64){
    float dsv, fv;
    sf_consume(ws, wsu, (TSTEPS - 1) & 3, 2, S, tid, dsv, fv);
    stO<F32>(p.out, TSTEPS * 64 + ((TSTEPS - 1) * 3 + 2) * 64 + tid, dsv);
  }
}

__global__ __launch_bounds__(NTHR, 2)
void trn_persist(Params p){
  __shared__ SharedMem S;
  // ---- runtime input-dtype detection from X's bit patterns ----
  if (threadIdx.x == 0){ S.bail = 0; S.badcnt = 0; }
  __syncthreads();
  if (threadIdx.x < 256){
    u16t u = ((const u16t*)p.X)[threadIdx.x];
    int e = (u >> 7) & 0xff;
    if (e == 0 || e >= 141) atomicAdd(&S.badcnt, 1);
  }
  __syncthreads();
  if (S.badcnt >= 3) run<true>(p, S);
  else               run<false>(p, S);
}

extern "C" void kernel_launch(void* const* d_in, const int* in_sizes, int n_in,
                              void* d_out, int out_size, void* d_ws, size_t ws_size,
                              hipStream_t stream){
  Params P;
  P.X      = d_in[0];
  P.eWih   = d_in[1];
  P.eWhh   = d_in[2];
  P.ebih   = d_in[3];
  P.ebhh   = d_in[4];
  P.dWih   = d_in[5];
  P.dWhh   = d_in[6];
  P.dbih   = d_in[7];
  P.dbhh   = d_in[8];
  P.hxW    = d_in[9];
  P.hxb    = d_in[10];
  P.cxW    = d_in[11];
  P.cxb    = d_in[12];
  P.fusW   = d_in[13];
  P.fusb_g = d_in[14];
  P.futW   = d_in[15];
  P.futb_g = d_in[16];
  P.clsW   = d_in[17];
  P.clsb_g = d_in[18];
  P.ws     = (float*)d_ws;
  P.out    = d_out;

  void* args[] = { &P };
  hipLaunchCooperativeKernel((void*)trn_persist, dim3(NWG), dim3(NTHR),
                             args, 0, stream);
}